// Round 1
// baseline (62.611 us; speedup 1.0000x reference)
//
#include <hip/hip_runtime.h>

#define F_      128
#define H_      16
#define E_      32
#define BTILE   64    // b rows per block (= lanes per wave)
#define FTILE   8     // features per block (= waves per block)
#define NTHREADS (FTILE * 64)   // 512

// Block: 8 waves. Wave w handles feature f = fblk*8 + w (wave-uniform -> all
// weight reads become scalar s_loads). Lane l handles b = bblk*64 + l.
// Each thread computes the full 32-wide output row for its (b, f), stages it
// in LDS, then the block writes 64 contiguous 1KB chunks coalesced.
__global__ __launch_bounds__(NTHREADS, 4)
void nfe_kernel(const float* __restrict__ x,
                const float* __restrict__ W1,
                const float* __restrict__ b1,
                const float* __restrict__ W2,
                const float* __restrict__ b2,
                float* __restrict__ out)
{
    // logical [BTILE][FTILE][8] float4 tile, e4 index XOR-swizzled by (b&7)
    __shared__ float4 lds4[BTILE * FTILE * 8];   // 64 KB

    const int tid  = threadIdx.x;
    const int wave = tid >> 6;       // f within tile
    const int lane = tid & 63;       // b within tile
    const int fblk = blockIdx.x;     // 16 blocks
    const int bblk = blockIdx.y;     // 256 blocks

    const int f = __builtin_amdgcn_readfirstlane(fblk * FTILE + wave);
    const int b = bblk * BTILE + lane;

    // wave-uniform weight pointers -> scalar loads
    const float* __restrict__ w1f = W1 + f * H_;
    const float* __restrict__ b1f = b1 + f * H_;
    const float* __restrict__ w2f = W2 + f * (H_ * E_);
    const float* __restrict__ b2f = b2 + f * E_;

    const float xv = x[b * F_ + f];

    float h[H_];
#pragma unroll
    for (int j = 0; j < H_; ++j) {
        float t = fmaf(xv, w1f[j], b1f[j]);
        h[j] = fmaxf(t, 0.0f);
    }

    float acc[E_];
#pragma unroll
    for (int e = 0; e < E_; ++e) acc[e] = b2f[e];
#pragma unroll
    for (int j = 0; j < H_; ++j) {
#pragma unroll
        for (int e = 0; e < E_; ++e)
            acc[e] = fmaf(h[j], w2f[j * E_ + e], acc[e]);
    }

    // stage into LDS: idx4 = b*64 + f*8 + (e4 ^ (b&7))
#pragma unroll
    for (int e4 = 0; e4 < 8; ++e4) {
        int idx4 = lane * (FTILE * 8) + wave * 8 + (e4 ^ (lane & 7));
        lds4[idx4] = make_float4(acc[e4 * 4 + 0], acc[e4 * 4 + 1],
                                 acc[e4 * 4 + 2], acc[e4 * 4 + 3]);
    }
    __syncthreads();

    // coalesced write-out: per b, FTILE*E_ = 256 floats = 64 float4 contiguous.
    // total 64 b * 64 = 4096 float4; 512 threads -> 8 iterations, each wave
    // writes one b's contiguous 1 KB chunk per iteration.
    float4* __restrict__ out4 = (float4*)out;
    const int base4 = (bblk * BTILE * F_ + fblk * FTILE) * (E_ / 4);
#pragma unroll
    for (int it = 0; it < 8; ++it) {
        int i4     = it * NTHREADS + tid;   // 0..4095
        int bb     = i4 >> 6;               // b within tile
        int within = i4 & 63;               // float4 within b's chunk
        int ff     = within >> 3;
        int e4     = within & 7;
        float4 v = lds4[bb * (FTILE * 8) + ff * 8 + (e4 ^ (bb & 7))];
        out4[base4 + bb * (F_ * E_ / 4) + within] = v;
    }
}

extern "C" void kernel_launch(void* const* d_in, const int* in_sizes, int n_in,
                              void* d_out, int out_size, void* d_ws, size_t ws_size,
                              hipStream_t stream) {
    const float* x  = (const float*)d_in[0];
    const float* W1 = (const float*)d_in[1];
    const float* b1 = (const float*)d_in[2];
    const float* W2 = (const float*)d_in[3];
    const float* b2 = (const float*)d_in[4];
    float* out = (float*)d_out;

    const int B = in_sizes[0] / F_;   // 16384
    dim3 grid(F_ / FTILE, B / BTILE); // (16, 256)
    nfe_kernel<<<grid, NTHREADS, 0, stream>>>(x, W1, b1, W2, b2, out);
}

// Round 3
// 56.739 us; speedup vs baseline: 1.1035x; 1.1035x over previous
//
#include <hip/hip_runtime.h>

#define F_   128
#define H_   16
#define E_   32
#define FG   8     // features per wave
#define BPW  64    // b rows per wave
#define WAVES 4
#define NTHREADS (WAVES * 64)   // 256

typedef float v4f __attribute__((ext_vector_type(4)));

// Wave owns (feature-group f0..f0+7) x (b-range of 64). Lane l -> feature
// f = f0 + (l>>3), e4 = l&7 (one float4 of E). Per b: one coalesced 1 KB
// wave store (64 consecutive float4), no LDS, no barriers. All weights in
// registers, amortized over the 64-b loop. x read per wave per b = 8
// consecutive floats = one cache line.
__global__ __launch_bounds__(NTHREADS, 4)
void nfe_kernel(const float* __restrict__ x,
                const float* __restrict__ W1,
                const float* __restrict__ b1,
                const float* __restrict__ W2,
                const float* __restrict__ b2,
                float* __restrict__ out)
{
    const int tid  = threadIdx.x;
    const int wave = tid >> 6;
    const int lane = tid & 63;

    const int f0 = blockIdx.x * FG;
    const int b0 = (blockIdx.y * WAVES + wave) * BPW;

    const int f  = f0 + (lane >> 3);
    const int e4 = lane & 7;

    // ---- per-lane weight fragments in registers ----
    float w1v[H_], b1v[H_];
    {
        const v4f* p1 = (const v4f*)(W1 + f * H_);
        const v4f* p2 = (const v4f*)(b1 + f * H_);
#pragma unroll
        for (int q = 0; q < 4; ++q) {
            v4f a = p1[q], c = p2[q];
            w1v[q*4+0]=a.x; w1v[q*4+1]=a.y; w1v[q*4+2]=a.z; w1v[q*4+3]=a.w;
            b1v[q*4+0]=c.x; b1v[q*4+1]=c.y; b1v[q*4+2]=c.z; b1v[q*4+3]=c.w;
        }
    }
    v4f w2v[H_];
#pragma unroll
    for (int j = 0; j < H_; ++j)
        w2v[j] = *(const v4f*)(W2 + (f * H_ + j) * E_ + e4 * 4);
    const v4f b2v = *(const v4f*)(b2 + f * E_ + e4 * 4);

    // ---- streaming loop over b ----
    const float* xp = x + b0 * F_ + f;
    v4f* op = (v4f*)out + (size_t)b0 * (F_ * E_ / 4)
            + f0 * (E_ / 4) + lane;

    float xv_next = *xp;
#pragma unroll 2
    for (int i = 0; i < BPW; ++i) {
        const float xv = xv_next;
        if (i + 1 < BPW) xv_next = xp[(i + 1) * F_];   // prefetch next b

        v4f acc = b2v;
#pragma unroll
        for (int j = 0; j < H_; ++j) {
            const float hj = fmaxf(fmaf(xv, w1v[j], b1v[j]), 0.0f);
            acc.x = fmaf(hj, w2v[j].x, acc.x);
            acc.y = fmaf(hj, w2v[j].y, acc.y);
            acc.z = fmaf(hj, w2v[j].z, acc.z);
            acc.w = fmaf(hj, w2v[j].w, acc.w);
        }
        __builtin_nontemporal_store(acc, op + i * (F_ * E_ / 4));
    }
}

extern "C" void kernel_launch(void* const* d_in, const int* in_sizes, int n_in,
                              void* d_out, int out_size, void* d_ws, size_t ws_size,
                              hipStream_t stream) {
    const float* x  = (const float*)d_in[0];
    const float* W1 = (const float*)d_in[1];
    const float* b1 = (const float*)d_in[2];
    const float* W2 = (const float*)d_in[3];
    const float* b2 = (const float*)d_in[4];
    float* out = (float*)d_out;

    const int B = in_sizes[0] / F_;                 // 16384
    dim3 grid(F_ / FG, B / (BPW * WAVES));          // (16, 64)
    nfe_kernel<<<grid, NTHREADS, 0, stream>>>(x, W1, b1, W2, b2, out);
}